// Round 1
// baseline (49423.441 us; speedup 1.0000x reference)
//
#include <hip/hip_runtime.h>
#include <math.h>

// ---------------------------------------------------------------------------
// Seq2SeqLSTM on MI355X -- Round 1: correctness-first multi-kernel baseline.
//
// Key structural facts used:
//  * Whole computation is independent per batch row (state, argmax, tokens).
//  * Decoder outer step t replays positions 0..t from the CARRIED state
//    (mask p<=t in the reference) -> 496 sequential stack-steps total.
//  * fp32 everywhere: argmax exactness forbids low precision on the chain.
//  * Layer-0 x-projections precomputed off the sequential path and cached
//    in ws (encoder: all 64 steps at once; decoder: one new position/step).
//
// ws layout (floats):
//   xp_e  [64][64][1024]   16 MB   encoder layer0 x-proj (+bias)
//   xp_d  [64][32][1024]    8 MB   decoder layer0 x-proj (+bias), cached
//   sh    [2][64][256]              h state (enc writes, dec carries)
//   sc    [2][64][256]              c state
//   pval  [64][1024] f32            per-(row, pred-WG) argmax partial value
//   pidx  [64][1024] i32            partial argmax index
//   buf   [64][32]   i32            token buffer (pos0 = BOS)
// total ~25.5 MB.
// ---------------------------------------------------------------------------

#define B     64
#define SLEN  64
#define TLEN  32
#define HID   256
#define EMBD  256
#define G4    1024       // 4*H
#define VOC   32000
#define NPRED 31         // TLEN-1

__device__ __forceinline__ float sigf(float x){ return 1.0f/(1.0f+__expf(-x)); }

// --------------------------------- init ------------------------------------
__global__ void k_init(const int* __restrict__ tgt, int* __restrict__ buf){
  int r = threadIdx.x;
  if (r < B) buf[r*TLEN] = tgt[r*TLEN];   // BOS token
}

// --------------------------------- xproj -----------------------------------
// out[(r*xp_npos + pos)*G4 + j] = b0[j] + sum_k emb[tok[r*tok_stride+pos]][k]*W[j][k]
// grid.x = 32 (j-slices of 32), grid.y = #positions. block = 256 (4 waves).
// lane = batch row r; wave = 8-wide j-subslice; W rows are wave-uniform ->
// scalar loads; x staged transposed in LDS (conflict-free lane reads).
__global__ __launch_bounds__(256) void k_xproj(
    const int* __restrict__ tok, int tok_stride, int pos0,
    const float* __restrict__ emb, const float* __restrict__ W,
    const float* __restrict__ b0, float* __restrict__ out, int xp_npos)
{
  __shared__ float xT[128][64];
  const int tid  = threadIdx.x;
  const int lane = tid & 63;
  const int wv   = __builtin_amdgcn_readfirstlane(tid >> 6);
  const int pos  = pos0 + blockIdx.y;
  const int jbase= blockIdx.x*32 + wv*8;

  const int rS = tid >> 2, klane = tid & 3;
  const int tokrow = tok[rS*tok_stride + pos];
  const float* xsrc = emb + (size_t)tokrow*EMBD;

  float acc[8];
  #pragma unroll
  for (int jj=0;jj<8;jj++) acc[jj]=0.f;

  for (int c=0;c<2;c++){
    __syncthreads();               // previous chunk fully consumed
    #pragma unroll
    for (int i=0;i<32;i++){
      int k = klane + 4*i;         // coalesced-ish global, k in [0,128)
      xT[k][rS] = xsrc[c*128 + k];
    }
    __syncthreads();
    for (int kc=0;kc<8;kc++){
      float x[16];
      #pragma unroll
      for (int i=0;i<16;i++) x[i] = xT[kc*16+i][lane];
      #pragma unroll
      for (int jj=0;jj<8;jj++){
        const float* Wp = W + (size_t)(jbase+jj)*EMBD + c*128 + kc*16;
        float s = 0.f;
        #pragma unroll
        for (int i=0;i<16;i++) s += Wp[i]*x[i];   // s_load W + v_fmac
        acc[jj] += s;
      }
    }
  }
  const int r = lane;
  #pragma unroll
  for (int jj=0;jj<8;jj++){
    int j = jbase+jj;
    out[((size_t)r*xp_npos + pos)*G4 + j] = acc[jj] + b0[j];
  }
}

// --------------------------------- chain -----------------------------------
// One WG per batch row; loops timesteps with state resident (h in LDS, c in
// regs). Thread j owns gate j. Layer0 uses precomputed x-proj; layer1 is full.
__device__ __forceinline__ float dot256(const float4* __restrict__ Wq,
                                        const float4* __restrict__ Xq){
  float a0=0.f,a1=0.f,a2=0.f,a3=0.f;
  #pragma unroll 2
  for (int kk=0; kk<64; kk+=4){
    float4 w0=Wq[kk+0], x0=Xq[kk+0]; a0 += w0.x*x0.x+w0.y*x0.y+w0.z*x0.z+w0.w*x0.w;
    float4 w1=Wq[kk+1], x1=Xq[kk+1]; a1 += w1.x*x1.x+w1.y*x1.y+w1.z*x1.z+w1.w*x1.w;
    float4 w2=Wq[kk+2], x2=Xq[kk+2]; a2 += w2.x*x2.x+w2.y*x2.y+w2.z*x2.z+w2.w*x2.w;
    float4 w3=Wq[kk+3], x3=Xq[kk+3]; a3 += w3.x*x3.x+w3.y*x3.y+w3.z*x3.z+w3.w*x3.w;
  }
  return (a0+a1)+(a2+a3);
}

__global__ __launch_bounds__(1024) void k_chain(
    const float* __restrict__ xp, int xp_npos, int nsteps,
    const float* __restrict__ Whh0, const float* __restrict__ Wih1,
    const float* __restrict__ Whh1, const float* __restrict__ b1,
    float* __restrict__ sh, float* __restrict__ sc, int initzero)
{
  __shared__ __align__(16) float h0s[HID];
  __shared__ __align__(16) float h1s[HID];
  __shared__ float g[G4];
  const int r = blockIdx.x;
  const int j = threadIdx.x;
  float c0=0.f, c1=0.f;
  if (j < HID){
    if (initzero){ h0s[j]=0.f; h1s[j]=0.f; }
    else {
      h0s[j] = sh[(size_t)r*HID + j];
      h1s[j] = sh[(size_t)(B + r)*HID + j];
      c0     = sc[(size_t)r*HID + j];
      c1     = sc[(size_t)(B + r)*HID + j];
    }
  }
  __syncthreads();

  const float4* W0  = (const float4*)(Whh0 + (size_t)j*HID);
  const float4* W1i = (const float4*)(Wih1 + (size_t)j*HID);
  const float4* W1h = (const float4*)(Whh1 + (size_t)j*HID);
  const float bias1 = b1[j];

  for (int p=0; p<nsteps; p++){
    // ---- layer0: g = xp[r][p] + Whh0*h0 (bias already folded into xp)
    float acc = xp[((size_t)r*xp_npos + p)*G4 + j]
              + dot256(W0, (const float4*)h0s);
    g[j] = acc;
    __syncthreads();
    if (j < HID){
      float gi=sigf(g[j]), gf=sigf(g[HID+j]);
      float gg=tanhf(g[2*HID+j]), go=sigf(g[3*HID+j]);
      c0 = gf*c0 + gi*gg;
      h0s[j] = go * tanhf(c0);
    }
    __syncthreads();
    // ---- layer1: g = Wih1*h0 + Whh1*h1 + b1
    acc = bias1 + dot256(W1i, (const float4*)h0s)
                + dot256(W1h, (const float4*)h1s);
    g[j] = acc;
    __syncthreads();
    if (j < HID){
      float gi=sigf(g[j]), gf=sigf(g[HID+j]);
      float gg=tanhf(g[2*HID+j]), go=sigf(g[3*HID+j]);
      c1 = gf*c1 + gi*gg;
      h1s[j] = go * tanhf(c1);
    }
    __syncthreads();
  }

  if (j < HID){
    sh[(size_t)r*HID + j]     = h0s[j];
    sh[(size_t)(B+r)*HID + j] = h1s[j];
    sc[(size_t)r*HID + j]     = c0;
    sc[(size_t)(B+r)*HID + j] = c1;
  }
}

// --------------------------------- pred ------------------------------------
// pred[r][t][v] = h1[r] . W_out[v] + b_out[v]; also per-WG argmax partials.
// grid = 1000 WGs x 32 vocab each; lane = row, wave = 8-vocab subslice.
__global__ __launch_bounds__(256) void k_pred(
    const float* __restrict__ h1, const float* __restrict__ Wout,
    const float* __restrict__ bout, float* __restrict__ dout, int t,
    float* __restrict__ pval, int* __restrict__ pidx)
{
  __shared__ float xT[128][64];
  __shared__ float cval[4][64];
  __shared__ int   cidx[4][64];
  const int tid  = threadIdx.x;
  const int lane = tid & 63;
  const int wv   = __builtin_amdgcn_readfirstlane(tid >> 6);
  const int vbase= blockIdx.x*32 + wv*8;

  const int rS = tid >> 2, klane = tid & 3;
  const float* xsrc = h1 + (size_t)rS*HID;

  float acc[8];
  #pragma unroll
  for (int vv=0;vv<8;vv++) acc[vv]=0.f;

  for (int c=0;c<2;c++){
    __syncthreads();
    #pragma unroll
    for (int i=0;i<32;i++){
      int k = klane + 4*i;
      xT[k][rS] = xsrc[c*128 + k];
    }
    __syncthreads();
    for (int kc=0;kc<8;kc++){
      float x[16];
      #pragma unroll
      for (int i=0;i<16;i++) x[i] = xT[kc*16+i][lane];
      #pragma unroll
      for (int vv=0;vv<8;vv++){
        const float* Wp = Wout + (size_t)(vbase+vv)*HID + c*128 + kc*16;
        float s = 0.f;
        #pragma unroll
        for (int i=0;i<16;i++) s += Wp[i]*x[i];
        acc[vv] += s;
      }
    }
  }

  const int r = lane;
  float best = -INFINITY; int bi = 0;
  #pragma unroll
  for (int vv=0; vv<8; vv++){
    int v = vbase + vv;
    float val = acc[vv] + bout[v];
    dout[((size_t)r*NPRED + t)*VOC + v] = val;
    if (val > best){ best = val; bi = v; }   // strict > keeps first max
  }
  cval[wv][lane] = best; cidx[wv][lane] = bi;
  __syncthreads();
  if (tid < 64){
    float bb = cval[0][tid]; int bbi = cidx[0][tid];
    #pragma unroll
    for (int w=1; w<4; w++){
      float v = cval[w][tid];
      if (v > bb){ bb = v; bbi = cidx[w][tid]; }  // ascending v: ties keep earlier
    }
    pval[(size_t)tid*1024 + blockIdx.x] = bb;
    pidx[(size_t)tid*1024 + blockIdx.x] = bbi;
  }
}

// ------------------------------ argmax final --------------------------------
__global__ __launch_bounds__(256) void k_amax(
    const float* __restrict__ pval, const int* __restrict__ pidx,
    int* __restrict__ buf, int t)
{
  __shared__ float sv[256]; __shared__ int si[256];
  const int r = blockIdx.x, tid = threadIdx.x;
  float best = -INFINITY; int bi = 0x7fffffff;
  for (int w = tid; w < 1000; w += 256){
    float v = pval[(size_t)r*1024 + w]; int ii = pidx[(size_t)r*1024 + w];
    if (v > best || (v == best && ii < bi)){ best = v; bi = ii; }
  }
  sv[tid] = best; si[tid] = bi;
  __syncthreads();
  for (int s2 = 128; s2 > 0; s2 >>= 1){
    if (tid < s2){
      float v = sv[tid+s2]; int ii = si[tid+s2];
      if (v > sv[tid] || (v == sv[tid] && ii < si[tid])){ sv[tid]=v; si[tid]=ii; }
    }
    __syncthreads();
  }
  if (tid == 0) buf[r*TLEN + t + 1] = si[0];
}

// -------------------------------- launch ------------------------------------
extern "C" void kernel_launch(void* const* d_in, const int* in_sizes, int n_in,
                              void* d_out, int out_size, void* d_ws, size_t ws_size,
                              hipStream_t stream)
{
  const int*   input_seq  = (const int*)d_in[0];
  const int*   target_seq = (const int*)d_in[1];
  const float* enc_emb = (const float*)d_in[2];
  const float* dec_emb = (const float*)d_in[3];
  const float* enc_Wih = (const float*)d_in[4];
  const float* enc_Whh = (const float*)d_in[5];
  const float* enc_b   = (const float*)d_in[6];
  const float* dec_Wih = (const float*)d_in[7];
  const float* dec_Whh = (const float*)d_in[8];
  const float* dec_b   = (const float*)d_in[9];
  const float* W_out   = (const float*)d_in[10];
  const float* b_out   = (const float*)d_in[11];
  float* out = (float*)d_out;

  float* ws   = (float*)d_ws;
  float* xp_e = ws;                              // B*SLEN*G4
  float* xp_d = xp_e + (size_t)B*SLEN*G4;        // B*TLEN*G4
  float* sh   = xp_d + (size_t)B*TLEN*G4;        // 2*B*HID
  float* sc   = sh + 2*B*HID;                    // 2*B*HID
  float* pval = sc + 2*B*HID;                    // B*1024
  int*   pidx = (int*)(pval + (size_t)B*1024);   // B*1024
  int*   buf  = pidx + (size_t)B*1024;           // B*TLEN

  k_init<<<1, 64, 0, stream>>>(target_seq, buf);

  // encoder: x-projections for all 64 steps, then the sequential chain
  k_xproj<<<dim3(32, SLEN), 256, 0, stream>>>(input_seq, SLEN, 0, enc_emb,
        enc_Wih, enc_b, xp_e, SLEN);
  k_chain<<<B, 1024, 0, stream>>>(xp_e, SLEN, SLEN,
        enc_Whh, enc_Wih + (size_t)G4*EMBD, enc_Whh + (size_t)G4*HID,
        enc_b + G4, sh, sc, 1);

  // decoder: greedy loop; each outer step replays positions 0..t
  for (int t = 0; t < NPRED; t++){
    k_xproj<<<dim3(32, 1), 256, 0, stream>>>(buf, TLEN, t, dec_emb,
        dec_Wih, dec_b, xp_d, TLEN);
    k_chain<<<B, 1024, 0, stream>>>(xp_d, TLEN, t+1,
        dec_Whh, dec_Wih + (size_t)G4*EMBD, dec_Whh + (size_t)G4*HID,
        dec_b + G4, sh, sc, 0);
    k_pred<<<1000, 256, 0, stream>>>(sh + (size_t)B*HID, W_out, b_out,
        out, t, pval, pidx);
    k_amax<<<B, 256, 0, stream>>>(pval, pidx, buf, t);
  }
}

// Round 2
// 15095.981 us; speedup vs baseline: 3.2739x; 3.2739x over previous
//
#include <hip/hip_runtime.h>
#include <math.h>

// ---------------------------------------------------------------------------
// Seq2SeqLSTM on MI355X -- Round 2: coalesced transposed-weight chain.
//
// Round-1 evidence: k_chain = 94% of time, 83 us/step, VALUBusy 2.4%,
// uncoalesced W rows (1KB lane stride -> 64 cache lines per wave load).
// Fix: transpose Whh0/Wih1/Whh1 into ws as WT[k][j]; thread layout
// (kq in 0..3) x (jg in 0..255); lane varies jg -> float4 loads over j are
// contiguous (1KB/wave-inst); h[k] is wave-uniform LDS broadcast.
// k-quarter partials reduced through LDS, activations on threads 0..255.
//
// ws layout (floats):
//   xp_e  [64][64][1024]  enc layer0 x-proj (+b)   4.19M
//   xp_d  [64][32][1024]  dec layer0 x-proj (+b)   2.10M (cached across t)
//   sh,sc [2][64][256]    states                   65K
//   pval/pidx [64][1024]  argmax partials          131K
//   buf   [64][32] i32    token buffer
//   6x WT [256][1024]     transposed weights       1.57M
// total ~32.3 MB.
// ---------------------------------------------------------------------------

#define B     64
#define SLEN  64
#define TLEN  32
#define HID   256
#define EMBD  256
#define G4    1024
#define VOC   32000
#define NPRED 31

__device__ __forceinline__ float sigf(float x){ return 1.0f/(1.0f+__expf(-x)); }

// --------------------------------- init ------------------------------------
__global__ void k_init(const int* __restrict__ tgt, int* __restrict__ buf){
  int r = threadIdx.x;
  if (r < B) buf[r*TLEN] = tgt[r*TLEN];
}

// ------------------------------- transpose ----------------------------------
// src [1024][256] -> dst [256][1024], 64x64 LDS tiles, conflict-free (+1 pad).
__global__ __launch_bounds__(256) void k_tr(const float* __restrict__ src,
                                            float* __restrict__ dst){
  __shared__ float t[64][65];
  const int r0 = blockIdx.x*64, c0 = blockIdx.y*64;
  const int lr = threadIdx.x>>6, lc = threadIdx.x&63;
  #pragma unroll
  for (int i=0;i<16;i++){
    int r = lr + i*4;
    t[r][lc] = src[(size_t)(r0+r)*256 + c0+lc];
  }
  __syncthreads();
  #pragma unroll
  for (int i=0;i<16;i++){
    int c = lr + i*4;
    dst[(size_t)(c0+c)*1024 + r0+lc] = t[lc][c];
  }
}

// --------------------------------- xproj -----------------------------------
__global__ __launch_bounds__(256) void k_xproj(
    const int* __restrict__ tok, int tok_stride, int pos0,
    const float* __restrict__ emb, const float* __restrict__ W,
    const float* __restrict__ b0, float* __restrict__ out, int xp_npos)
{
  __shared__ float xT[128][64];
  const int tid  = threadIdx.x;
  const int lane = tid & 63;
  const int wv   = __builtin_amdgcn_readfirstlane(tid >> 6);
  const int pos  = pos0 + blockIdx.y;
  const int jbase= blockIdx.x*32 + wv*8;

  const int rS = tid >> 2, klane = tid & 3;
  const int tokrow = tok[rS*tok_stride + pos];
  const float* xsrc = emb + (size_t)tokrow*EMBD;

  float acc[8];
  #pragma unroll
  for (int jj=0;jj<8;jj++) acc[jj]=0.f;

  for (int c=0;c<2;c++){
    __syncthreads();
    #pragma unroll
    for (int i=0;i<32;i++){
      int k = klane + 4*i;
      xT[k][rS] = xsrc[c*128 + k];
    }
    __syncthreads();
    for (int kc=0;kc<8;kc++){
      float x[16];
      #pragma unroll
      for (int i=0;i<16;i++) x[i] = xT[kc*16+i][lane];
      #pragma unroll
      for (int jj=0;jj<8;jj++){
        const float* Wp = W + (size_t)(jbase+jj)*EMBD + c*128 + kc*16;
        float s = 0.f;
        #pragma unroll
        for (int i=0;i<16;i++) s += Wp[i]*x[i];
        acc[jj] += s;
      }
    }
  }
  const int r = lane;
  #pragma unroll
  for (int jj=0;jj<8;jj++){
    int j = jbase+jj;
    out[((size_t)r*xp_npos + pos)*G4 + j] = acc[jj] + b0[j];
  }
}

// --------------------------------- chain -----------------------------------
// WT layout: [k][j] (k=0..255 over h, j=0..1023 gate rows). Thread (kq,jg)
// accumulates k in [kq*64, kq*64+64) for gates 4jg..4jg+3 with coalesced
// float4 loads; h[k] wave-uniform ds_read_b128 broadcast.
__device__ __forceinline__ float4 dotpart(const float4* __restrict__ Wt,
                                          const float* __restrict__ hs,
                                          int kq, int jg){
  float ax=0.f, ay=0.f, az=0.f, aw=0.f;
  const float4* __restrict__ hq = (const float4*)(hs + (kq<<6));
  const float4* __restrict__ w  = Wt + (size_t)(kq<<6)*256 + jg;
  #pragma unroll 4
  for (int kk=0; kk<16; ++kk){
    float4 h4 = hq[kk];
    float4 w0 = w[0];
    float4 w1 = w[256];
    float4 w2 = w[512];
    float4 w3 = w[768];
    ax += w0.x*h4.x; ay += w0.y*h4.x; az += w0.z*h4.x; aw += w0.w*h4.x;
    ax += w1.x*h4.y; ay += w1.y*h4.y; az += w1.z*h4.y; aw += w1.w*h4.y;
    ax += w2.x*h4.z; ay += w2.y*h4.z; az += w2.z*h4.z; aw += w2.w*h4.z;
    ax += w3.x*h4.w; ay += w3.y*h4.w; az += w3.z*h4.w; aw += w3.w*h4.w;
    w += 1024;
  }
  return make_float4(ax,ay,az,aw);
}

__global__ __launch_bounds__(1024) void k_chain2(
    const float* __restrict__ xp, int xp_npos, int nsteps,
    const float* __restrict__ T0, const float* __restrict__ T1i,
    const float* __restrict__ T1h, const float* __restrict__ b1,
    float* __restrict__ sh, float* __restrict__ sc, int initzero)
{
  __shared__ __align__(16) float h0s[HID];
  __shared__ __align__(16) float h1s[HID];
  __shared__ __align__(16) float part[4][G4];
  __shared__ float xps[G4];
  __shared__ float b1s[G4];
  const int r   = blockIdx.x;
  const int tid = threadIdx.x;
  const int kq  = tid >> 8;
  const int jg  = tid & 255;

  b1s[tid] = b1[tid];
  float c0 = 0.f, c1 = 0.f;
  if (tid < HID){
    if (initzero){ h0s[tid]=0.f; h1s[tid]=0.f; }
    else {
      h0s[tid] = sh[(size_t)r*HID + tid];
      h1s[tid] = sh[(size_t)(B+r)*HID + tid];
      c0       = sc[(size_t)r*HID + tid];
      c1       = sc[(size_t)(B+r)*HID + tid];
    }
  }
  __syncthreads();

  const float4* T04  = (const float4*)T0;
  const float4* T1i4 = (const float4*)T1i;
  const float4* T1h4 = (const float4*)T1h;
  const float*  xpr  = xp + (size_t)r*xp_npos*G4;

  for (int p = 0; p < nsteps; ++p){
    float xv = xpr[(size_t)p*G4 + tid];        // issue early, off critical path
    float4 p0 = dotpart(T04, h0s, kq, jg);     // layer0 recurrent matvec part
    xps[tid] = xv;
    *(float4*)&part[kq][jg<<2] = p0;
    __syncthreads();
    if (tid < HID){
      float gi = part[0][tid]        +part[1][tid]        +part[2][tid]        +part[3][tid]        + xps[tid];
      float gf = part[0][HID+tid]    +part[1][HID+tid]    +part[2][HID+tid]    +part[3][HID+tid]    + xps[HID+tid];
      float gg = part[0][2*HID+tid]  +part[1][2*HID+tid]  +part[2][2*HID+tid]  +part[3][2*HID+tid]  + xps[2*HID+tid];
      float go = part[0][3*HID+tid]  +part[1][3*HID+tid]  +part[2][3*HID+tid]  +part[3][3*HID+tid]  + xps[3*HID+tid];
      c0 = sigf(gf)*c0 + sigf(gi)*tanhf(gg);
      h0s[tid] = sigf(go)*tanhf(c0);
    }
    __syncthreads();
    float4 p1 = dotpart(T1i4, h0s, kq, jg);    // layer1: Wih1*h0 + Whh1*h1
    float4 p2 = dotpart(T1h4, h1s, kq, jg);
    p1.x += p2.x; p1.y += p2.y; p1.z += p2.z; p1.w += p2.w;
    *(float4*)&part[kq][jg<<2] = p1;
    __syncthreads();
    if (tid < HID){
      float gi = part[0][tid]        +part[1][tid]        +part[2][tid]        +part[3][tid]        + b1s[tid];
      float gf = part[0][HID+tid]    +part[1][HID+tid]    +part[2][HID+tid]    +part[3][HID+tid]    + b1s[HID+tid];
      float gg = part[0][2*HID+tid]  +part[1][2*HID+tid]  +part[2][2*HID+tid]  +part[3][2*HID+tid]  + b1s[2*HID+tid];
      float go = part[0][3*HID+tid]  +part[1][3*HID+tid]  +part[2][3*HID+tid]  +part[3][3*HID+tid]  + b1s[3*HID+tid];
      c1 = sigf(gf)*c1 + sigf(gi)*tanhf(gg);
      h1s[tid] = sigf(go)*tanhf(c1);
    }
    __syncthreads();
  }

  if (tid < HID){
    sh[(size_t)r*HID + tid]     = h0s[tid];
    sh[(size_t)(B+r)*HID + tid] = h1s[tid];
    sc[(size_t)r*HID + tid]     = c0;
    sc[(size_t)(B+r)*HID + tid] = c1;
  }
}

// --------------------------------- pred ------------------------------------
__global__ __launch_bounds__(256) void k_pred(
    const float* __restrict__ h1, const float* __restrict__ Wout,
    const float* __restrict__ bout, float* __restrict__ dout, int t,
    float* __restrict__ pval, int* __restrict__ pidx)
{
  __shared__ float xT[128][64];
  __shared__ float cval[4][64];
  __shared__ int   cidx[4][64];
  const int tid  = threadIdx.x;
  const int lane = tid & 63;
  const int wv   = __builtin_amdgcn_readfirstlane(tid >> 6);
  const int vbase= blockIdx.x*32 + wv*8;

  const int rS = tid >> 2, klane = tid & 3;
  const float* xsrc = h1 + (size_t)rS*HID;

  float acc[8];
  #pragma unroll
  for (int vv=0;vv<8;vv++) acc[vv]=0.f;

  for (int c=0;c<2;c++){
    __syncthreads();
    #pragma unroll
    for (int i=0;i<32;i++){
      int k = klane + 4*i;
      xT[k][rS] = xsrc[c*128 + k];
    }
    __syncthreads();
    for (int kc=0;kc<8;kc++){
      float x[16];
      #pragma unroll
      for (int i=0;i<16;i++) x[i] = xT[kc*16+i][lane];
      #pragma unroll
      for (int vv=0;vv<8;vv++){
        const float* Wp = Wout + (size_t)(vbase+vv)*HID + c*128 + kc*16;
        float s = 0.f;
        #pragma unroll
        for (int i=0;i<16;i++) s += Wp[i]*x[i];
        acc[vv] += s;
      }
    }
  }

  const int r = lane;
  float best = -INFINITY; int bi = 0;
  #pragma unroll
  for (int vv=0; vv<8; vv++){
    int v = vbase + vv;
    float val = acc[vv] + bout[v];
    dout[((size_t)r*NPRED + t)*VOC + v] = val;
    if (val > best){ best = val; bi = v; }
  }
  cval[wv][lane] = best; cidx[wv][lane] = bi;
  __syncthreads();
  if (tid < 64){
    float bb = cval[0][tid]; int bbi = cidx[0][tid];
    #pragma unroll
    for (int w=1; w<4; w++){
      float v = cval[w][tid];
      if (v > bb){ bb = v; bbi = cidx[w][tid]; }
    }
    pval[(size_t)tid*1024 + blockIdx.x] = bb;
    pidx[(size_t)tid*1024 + blockIdx.x] = bbi;
  }
}

// ------------------------------ argmax final --------------------------------
__global__ __launch_bounds__(256) void k_amax(
    const float* __restrict__ pval, const int* __restrict__ pidx,
    int* __restrict__ buf, int t)
{
  __shared__ float sv[256]; __shared__ int si[256];
  const int r = blockIdx.x, tid = threadIdx.x;
  float best = -INFINITY; int bi = 0x7fffffff;
  for (int w = tid; w < 1000; w += 256){
    float v = pval[(size_t)r*1024 + w]; int ii = pidx[(size_t)r*1024 + w];
    if (v > best || (v == best && ii < bi)){ best = v; bi = ii; }
  }
  sv[tid] = best; si[tid] = bi;
  __syncthreads();
  for (int s2 = 128; s2 > 0; s2 >>= 1){
    if (tid < s2){
      float v = sv[tid+s2]; int ii = si[tid+s2];
      if (v > sv[tid] || (v == sv[tid] && ii < si[tid])){ sv[tid]=v; si[tid]=ii; }
    }
    __syncthreads();
  }
  if (tid == 0) buf[r*TLEN + t + 1] = si[0];
}

// -------------------------------- launch ------------------------------------
extern "C" void kernel_launch(void* const* d_in, const int* in_sizes, int n_in,
                              void* d_out, int out_size, void* d_ws, size_t ws_size,
                              hipStream_t stream)
{
  const int*   input_seq  = (const int*)d_in[0];
  const int*   target_seq = (const int*)d_in[1];
  const float* enc_emb = (const float*)d_in[2];
  const float* dec_emb = (const float*)d_in[3];
  const float* enc_Wih = (const float*)d_in[4];
  const float* enc_Whh = (const float*)d_in[5];
  const float* enc_b   = (const float*)d_in[6];
  const float* dec_Wih = (const float*)d_in[7];
  const float* dec_Whh = (const float*)d_in[8];
  const float* dec_b   = (const float*)d_in[9];
  const float* W_out   = (const float*)d_in[10];
  const float* b_out   = (const float*)d_in[11];
  float* out = (float*)d_out;

  float* ws   = (float*)d_ws;
  float* xp_e = ws;                              // B*SLEN*G4
  float* xp_d = xp_e + (size_t)B*SLEN*G4;        // B*TLEN*G4
  float* sh   = xp_d + (size_t)B*TLEN*G4;        // 2*B*HID
  float* sc   = sh + 2*B*HID;                    // 2*B*HID
  float* pval = sc + 2*B*HID;                    // B*1024
  int*   pidx = (int*)(pval + (size_t)B*1024);   // B*1024
  int*   buf  = pidx + (size_t)B*1024;           // B*TLEN
  float* wt   = (float*)(buf + B*TLEN);
  float* tE0  = wt;                 // enc Whh0^T  [256][1024]
  float* tE1i = tE0  + 256*G4;      // enc Wih1^T
  float* tE1h = tE1i + 256*G4;      // enc Whh1^T
  float* tD0  = tE1h + 256*G4;      // dec Whh0^T
  float* tD1i = tD0  + 256*G4;      // dec Wih1^T
  float* tD1h = tD1i + 256*G4;      // dec Whh1^T

  k_init<<<1, 64, 0, stream>>>(target_seq, buf);

  // one-time weight transposes (re-run every call: determinism requirement)
  dim3 trg(16, 4);
  k_tr<<<trg, 256, 0, stream>>>(enc_Whh,                      tE0);
  k_tr<<<trg, 256, 0, stream>>>(enc_Wih + (size_t)G4*EMBD,    tE1i);
  k_tr<<<trg, 256, 0, stream>>>(enc_Whh + (size_t)G4*HID,     tE1h);
  k_tr<<<trg, 256, 0, stream>>>(dec_Whh,                      tD0);
  k_tr<<<trg, 256, 0, stream>>>(dec_Wih + (size_t)G4*EMBD,    tD1i);
  k_tr<<<trg, 256, 0, stream>>>(dec_Whh + (size_t)G4*HID,     tD1h);

  // encoder
  k_xproj<<<dim3(32, SLEN), 256, 0, stream>>>(input_seq, SLEN, 0, enc_emb,
        enc_Wih, enc_b, xp_e, SLEN);
  k_chain2<<<B, 1024, 0, stream>>>(xp_e, SLEN, SLEN,
        tE0, tE1i, tE1h, enc_b + G4, sh, sc, 1);

  // decoder greedy loop (outer step t replays positions 0..t)
  for (int t = 0; t < NPRED; t++){
    k_xproj<<<dim3(32, 1), 256, 0, stream>>>(buf, TLEN, t, dec_emb,
        dec_Wih, dec_b, xp_d, TLEN);
    k_chain2<<<B, 1024, 0, stream>>>(xp_d, TLEN, t+1,
        tD0, tD1i, tD1h, dec_b + G4, sh, sc, 0);
    k_pred<<<1000, 256, 0, stream>>>(sh + (size_t)B*HID, W_out, b_out,
        out, t, pval, pidx);
    k_amax<<<B, 256, 0, stream>>>(pval, pidx, buf, t);
  }
}

// Round 3
// 11463.105 us; speedup vs baseline: 4.3115x; 1.3169x over previous
//
#include <hip/hip_runtime.h>
#include <math.h>

// ---------------------------------------------------------------------------
// Seq2SeqLSTM on MI355X -- Round 3: lane=row chain, j/k-split across 64 WGs,
// one device-scope barrier per step.
//
// Round-2 evidence: chain = 85% of time at 22.8us/step, VALUBusy 5%, occupancy
// 12% (64 row-WGs on 64 CUs), per-CU weight stream 3MB/step = 131 GB/s ~= the
// per-CU L1-miss-path ceiling. Any per-row WG re-streams all weights; the fix
// is splitting the weight matrix across CUs and exchanging the tiny h vectors.
//
// New chain structure:
//   B=64 rows = 64 lanes. 64 WGs x 1024 threads = 1024 waves
//   wave (jsub,kq): j-column j = blockIdx*4+jsub, k-slice [kq*64,kq*64+64)
//   weights wave-uniform (scalar loads from ORIGINAL row-major layout);
//   h0/h1 in LDS [k][r] (bank-conflict-free); partials reduced through LDS;
//   kq=0 waves do activations, keep c-state in registers, publish h to
//   double-buffered gmem slabs (h0T/h1T) reloaded into LDS next phase.
//   Phase q: L0(step q) || L1(step q-1)  ->  ONE grid barrier per phase.
//   Grid barrier: one-shot atomic counter per phase (pre-zeroed), agent-scope
//   release/acquire fences (cooperative-groups pattern).
// ---------------------------------------------------------------------------

#define B     64
#define SLEN  64
#define TLEN  32
#define HID   256
#define EMBD  256
#define G4    1024
#define VOC   32000
#define NPRED 31
#define NWG   64

__device__ __forceinline__ float sigf(float x){ return 1.0f/(1.0f+__expf(-x)); }

// --------------------------------- init ------------------------------------
__global__ void k_init(const int* __restrict__ tgt, int* __restrict__ buf){
  int r = threadIdx.x;
  if (r < B) buf[r*TLEN] = tgt[r*TLEN];
}

__global__ void k_zero(int* __restrict__ ctr){
  ctr[threadIdx.x] = 0;
}

// --------------------------------- xproj -----------------------------------
// out[(pos*G4 + j)*64 + r] = b0[j] + sum_k emb[tok[r]][k] * W[j][k]
// (transposed output layout: lane=r contiguous -> coalesced 256B stores)
__global__ __launch_bounds__(256) void k_xproj(
    const int* __restrict__ tok, int tok_stride, int pos0,
    const float* __restrict__ emb, const float* __restrict__ W,
    const float* __restrict__ b0, float* __restrict__ out)
{
  __shared__ float xT[128][64];
  const int tid  = threadIdx.x;
  const int lane = tid & 63;
  const int wv   = __builtin_amdgcn_readfirstlane(tid >> 6);
  const int pos  = pos0 + blockIdx.y;
  const int jbase= blockIdx.x*32 + wv*8;

  const int rS = tid >> 2, klane = tid & 3;
  const int tokrow = tok[rS*tok_stride + pos];
  const float* xsrc = emb + (size_t)tokrow*EMBD;

  float acc[8];
  #pragma unroll
  for (int jj=0;jj<8;jj++) acc[jj]=0.f;

  for (int c=0;c<2;c++){
    __syncthreads();
    #pragma unroll
    for (int i=0;i<32;i++){
      int k = klane + 4*i;
      xT[k][rS] = xsrc[c*128 + k];
    }
    __syncthreads();
    for (int kc=0;kc<8;kc++){
      float x[16];
      #pragma unroll
      for (int i=0;i<16;i++) x[i] = xT[kc*16+i][lane];
      #pragma unroll
      for (int jj=0;jj<8;jj++){
        const float* Wp = W + (size_t)(jbase+jj)*EMBD + c*128 + kc*16;
        float s = 0.f;
        #pragma unroll
        for (int i=0;i<16;i++) s += Wp[i]*x[i];
        acc[jj] += s;
      }
    }
  }
  #pragma unroll
  for (int jj=0;jj<8;jj++){
    int j = jbase+jj;
    out[((size_t)pos*G4 + j)*64 + lane] = acc[jj] + b0[j];
  }
}

// ---------------------------- device barrier --------------------------------
__device__ __forceinline__ void gbar(int* __restrict__ c){
  __syncthreads();
  if (threadIdx.x == 0){
    __builtin_amdgcn_fence(__ATOMIC_RELEASE, "agent");
    __hip_atomic_fetch_add(c, 1, __ATOMIC_RELAXED, __HIP_MEMORY_SCOPE_AGENT);
    while (__hip_atomic_load(c, __ATOMIC_RELAXED, __HIP_MEMORY_SCOPE_AGENT) < NWG)
      __builtin_amdgcn_s_sleep(1);
    __builtin_amdgcn_fence(__ATOMIC_ACQUIRE, "agent");
  }
  __syncthreads();
}

// --------------------------------- chain -----------------------------------
// xp layout: [p][1024][64]. Weights in ORIGINAL [1024][256] row-major.
// h0T/h1T: [2][256][64] double-buffered gmem exchange slabs.
// h0P/h1P/c0P/c1P: [256][64] persistent state across dispatches.
__global__ __launch_bounds__(1024, 4) void k_chain3(
    const float* __restrict__ xp, int nsteps,
    const float* __restrict__ Whh0, const float* __restrict__ Wih1,
    const float* __restrict__ Whh1, const float* __restrict__ b1,
    float* __restrict__ h0P, float* __restrict__ h1P,
    float* __restrict__ c0P, float* __restrict__ c1P,
    float* __restrict__ h0T, float* __restrict__ h1T,
    int* __restrict__ ctr, int initzero)
{
  __shared__ __align__(16) float h0s[256][64];   // 64 KB
  __shared__ __align__(16) float h1s[256][64];   // 64 KB
  __shared__ float part[16][4][64];              // 16 KB
  const int tid  = threadIdx.x;
  const int lane = tid & 63;
  const int wv   = __builtin_amdgcn_readfirstlane(tid >> 6);
  const int jsub = wv & 3, kq = wv >> 2;
  const int j    = blockIdx.x*4 + jsub;
  const int k0   = kq << 6;

  // weight row pointers (all wave-uniform -> scalar loads)
  const float* Wr0 = Whh0 + ((size_t)(0*HID+j))*HID + k0;
  const float* Wr1 = Whh0 + ((size_t)(1*HID+j))*HID + k0;
  const float* Wr2 = Whh0 + ((size_t)(2*HID+j))*HID + k0;
  const float* Wr3 = Whh0 + ((size_t)(3*HID+j))*HID + k0;
  const float* Wi0 = Wih1 + ((size_t)(0*HID+j))*HID + k0;
  const float* Wi1 = Wih1 + ((size_t)(1*HID+j))*HID + k0;
  const float* Wi2 = Wih1 + ((size_t)(2*HID+j))*HID + k0;
  const float* Wi3 = Wih1 + ((size_t)(3*HID+j))*HID + k0;
  const float* Wh0 = Whh1 + ((size_t)(0*HID+j))*HID + k0;
  const float* Wh1 = Whh1 + ((size_t)(1*HID+j))*HID + k0;
  const float* Wh2 = Whh1 + ((size_t)(2*HID+j))*HID + k0;
  const float* Wh3 = Whh1 + ((size_t)(3*HID+j))*HID + k0;

  float c0 = 0.f, c1 = 0.f;
  if (wv < 4 && !initzero){
    c0 = c0P[j*64 + lane];
    c1 = c1P[j*64 + lane];
  }

  for (int q = 0; q <= nsteps; ++q){
    if (q) gbar(ctr + q - 1);

    // act-wave prefetch: xp rows for step q (gate rows j, 256+j, 512+j, 768+j)
    float xv0=0.f, xv1=0.f, xv2=0.f, xv3=0.f;
    if (wv < 4 && q < nsteps){
      const float* xq = xp + ((size_t)q*G4)*64 + lane;
      xv0 = xq[(0*HID+j)*64]; xv1 = xq[(1*HID+j)*64];
      xv2 = xq[(2*HID+j)*64]; xv3 = xq[(3*HID+j)*64];
    }

    // cooperative load h0s <- h(0)(q-1); h1s <- h(1)(q-2)
    {
      float4* d0 = (float4*)&h0s[0][0];
      float4* d1 = (float4*)&h1s[0][0];
      if (initzero && q == 0){
        float4 z = make_float4(0.f,0.f,0.f,0.f);
        #pragma unroll
        for (int i=0;i<4;i++) d0[tid + i*1024] = z;
      } else {
        const float4* s0 = (const float4*)(q==0 ? h0P : h0T + (size_t)((q-1)&1)*16384);
        #pragma unroll
        for (int i=0;i<4;i++) d0[tid + i*1024] = s0[tid + i*1024];
      }
      if (initzero && q <= 1){
        float4 z = make_float4(0.f,0.f,0.f,0.f);
        #pragma unroll
        for (int i=0;i<4;i++) d1[tid + i*1024] = z;
      } else {
        const float4* s1 = (const float4*)(q<=1 ? h1P : h1T + (size_t)(q&1)*16384);
        #pragma unroll
        for (int i=0;i<4;i++) d1[tid + i*1024] = s1[tid + i*1024];
      }
    }
    __syncthreads();   // h0s/h1s ready

    // ---- L0 partials for step q (skip at q==nsteps)
    float a0=0.f,a1=0.f,a2=0.f,a3=0.f;
    if (q < nsteps){
      #pragma unroll 8
      for (int k=0;k<64;k++){
        float h = h0s[k0+k][lane];
        a0 += Wr0[k]*h; a1 += Wr1[k]*h; a2 += Wr2[k]*h; a3 += Wr3[k]*h;
      }
      part[wv][0][lane]=a0; part[wv][1][lane]=a1;
      part[wv][2][lane]=a2; part[wv][3][lane]=a3;
    }
    __syncthreads();   // pL0 complete

    // act0 (kq==0 waves): reduce + activate + publish h0(q)
    if (wv < 4 && q < nsteps){
      float g0=xv0, g1=xv1, g2=xv2, g3=xv3;
      #pragma unroll
      for (int kk=0;kk<4;kk++){
        g0 += part[kk*4+wv][0][lane]; g1 += part[kk*4+wv][1][lane];
        g2 += part[kk*4+wv][2][lane]; g3 += part[kk*4+wv][3][lane];
      }
      c0 = sigf(g1)*c0 + sigf(g0)*tanhf(g2);
      float h = sigf(g3)*tanhf(c0);
      h0T[(size_t)(q&1)*16384 + j*64 + lane] = h;
      if (q == nsteps-1) h0P[j*64 + lane] = h;
    }

    // ---- L1 partials for step q-1 (uses h0s = h0(q-1), h1s = h1(q-2))
    float b0a=0.f,b1a=0.f,b2a=0.f,b3a=0.f;
    if (q >= 1){
      #pragma unroll 8
      for (int k=0;k<64;k++){
        float ha = h0s[k0+k][lane];
        float hb = h1s[k0+k][lane];
        b0a += Wi0[k]*ha + Wh0[k]*hb;
        b1a += Wi1[k]*ha + Wh1[k]*hb;
        b2a += Wi2[k]*ha + Wh2[k]*hb;
        b3a += Wi3[k]*ha + Wh3[k]*hb;
      }
    }
    __syncthreads();   // act0 done reading pL0; safe to overwrite
    if (q >= 1){
      part[wv][0][lane]=b0a; part[wv][1][lane]=b1a;
      part[wv][2][lane]=b2a; part[wv][3][lane]=b3a;
    }
    __syncthreads();   // pL1 complete

    // act1 (kq==0 waves): reduce + activate + publish h1(q-1)
    if (wv < 4 && q >= 1){
      float g0=b1[0*HID+j], g1=b1[1*HID+j], g2=b1[2*HID+j], g3=b1[3*HID+j];
      #pragma unroll
      for (int kk=0;kk<4;kk++){
        g0 += part[kk*4+wv][0][lane]; g1 += part[kk*4+wv][1][lane];
        g2 += part[kk*4+wv][2][lane]; g3 += part[kk*4+wv][3][lane];
      }
      c1 = sigf(g1)*c1 + sigf(g0)*tanhf(g2);
      float h = sigf(g3)*tanhf(c1);
      h1T[(size_t)((q-1)&1)*16384 + j*64 + lane] = h;
      if (q == nsteps) h1P[j*64 + lane] = h;
    }
  }

  if (wv < 4){
    c0P[j*64 + lane] = c0;
    c1P[j*64 + lane] = c1;
  }
}

// --------------------------------- pred ------------------------------------
// h1 layout now [k][r] ([256][64]); staging is a flat coalesced copy.
__global__ __launch_bounds__(256) void k_pred(
    const float* __restrict__ h1, const float* __restrict__ Wout,
    const float* __restrict__ bout, float* __restrict__ dout, int t,
    float* __restrict__ pval, int* __restrict__ pidx)
{
  __shared__ float xT[128][64];
  __shared__ float cval[4][64];
  __shared__ int   cidx[4][64];
  const int tid  = threadIdx.x;
  const int lane = tid & 63;
  const int wv   = __builtin_amdgcn_readfirstlane(tid >> 6);
  const int vbase= blockIdx.x*32 + wv*8;

  float acc[8];
  #pragma unroll
  for (int vv=0;vv<8;vv++) acc[vv]=0.f;

  for (int c=0;c<2;c++){
    __syncthreads();
    {
      const float4* s4 = (const float4*)(h1 + c*8192);
      float4* d4 = (float4*)&xT[0][0];
      #pragma unroll
      for (int i=0;i<8;i++) d4[tid + i*256] = s4[tid + i*256];
    }
    __syncthreads();
    for (int kc=0;kc<8;kc++){
      float x[16];
      #pragma unroll
      for (int i=0;i<16;i++) x[i] = xT[kc*16+i][lane];
      #pragma unroll
      for (int vv=0;vv<8;vv++){
        const float* Wp = Wout + (size_t)(vbase+vv)*HID + c*128 + kc*16;
        float s = 0.f;
        #pragma unroll
        for (int i=0;i<16;i++) s += Wp[i]*x[i];
        acc[vv] += s;
      }
    }
  }

  const int r = lane;
  float best = -INFINITY; int bi = 0;
  #pragma unroll
  for (int vv=0; vv<8; vv++){
    int v = vbase + vv;
    float val = acc[vv] + bout[v];
    dout[((size_t)r*NPRED + t)*VOC + v] = val;
    if (val > best){ best = val; bi = v; }
  }
  cval[wv][lane] = best; cidx[wv][lane] = bi;
  __syncthreads();
  if (tid < 64){
    float bb = cval[0][tid]; int bbi = cidx[0][tid];
    #pragma unroll
    for (int w=1; w<4; w++){
      float v = cval[w][tid];
      if (v > bb){ bb = v; bbi = cidx[w][tid]; }
    }
    pval[(size_t)tid*1024 + blockIdx.x] = bb;
    pidx[(size_t)tid*1024 + blockIdx.x] = bbi;
  }
}

// ------------------------------ argmax final --------------------------------
__global__ __launch_bounds__(256) void k_amax(
    const float* __restrict__ pval, const int* __restrict__ pidx,
    int* __restrict__ buf, int t)
{
  __shared__ float sv[256]; __shared__ int si[256];
  const int r = blockIdx.x, tid = threadIdx.x;
  float best = -INFINITY; int bi = 0x7fffffff;
  for (int w = tid; w < 1000; w += 256){
    float v = pval[(size_t)r*1024 + w]; int ii = pidx[(size_t)r*1024 + w];
    if (v > best || (v == best && ii < bi)){ best = v; bi = ii; }
  }
  sv[tid] = best; si[tid] = bi;
  __syncthreads();
  for (int s2 = 128; s2 > 0; s2 >>= 1){
    if (tid < s2){
      float v = sv[tid+s2]; int ii = si[tid+s2];
      if (v > sv[tid] || (v == sv[tid] && ii < si[tid])){ sv[tid]=v; si[tid]=ii; }
    }
    __syncthreads();
  }
  if (tid == 0) buf[r*TLEN + t + 1] = si[0];
}

// -------------------------------- launch ------------------------------------
extern "C" void kernel_launch(void* const* d_in, const int* in_sizes, int n_in,
                              void* d_out, int out_size, void* d_ws, size_t ws_size,
                              hipStream_t stream)
{
  const int*   input_seq  = (const int*)d_in[0];
  const int*   target_seq = (const int*)d_in[1];
  const float* enc_emb = (const float*)d_in[2];
  const float* dec_emb = (const float*)d_in[3];
  const float* enc_Wih = (const float*)d_in[4];
  const float* enc_Whh = (const float*)d_in[5];
  const float* enc_b   = (const float*)d_in[6];
  const float* dec_Wih = (const float*)d_in[7];
  const float* dec_Whh = (const float*)d_in[8];
  const float* dec_b   = (const float*)d_in[9];
  const float* W_out   = (const float*)d_in[10];
  const float* b_out   = (const float*)d_in[11];
  float* out = (float*)d_out;

  float* ws   = (float*)d_ws;
  float* xp_e = ws;                               // 64*1024*64
  float* xp_d = xp_e + (size_t)SLEN*G4*64;        // 32*1024*64
  float* h0P  = xp_d + (size_t)TLEN*G4*64;        // 256*64
  float* h1P  = h0P + HID*64;
  float* c0P  = h1P + HID*64;
  float* c1P  = c0P + HID*64;
  float* h0T  = c1P + HID*64;                     // 2*256*64
  float* h1T  = h0T + 2*HID*64;                   // 2*256*64
  float* pval = h1T + 2*HID*64;                   // 64*1024
  int*   pidx = (int*)(pval + (size_t)B*1024);    // 64*1024
  int*   buf  = pidx + (size_t)B*1024;            // 64*32
  int*   ctr  = buf + B*TLEN;                     // 1024 barrier slots

  k_init<<<1, 64, 0, stream>>>(target_seq, buf);
  k_zero<<<1, 1024, 0, stream>>>(ctr);

  // encoder
  k_xproj<<<dim3(32, SLEN), 256, 0, stream>>>(input_seq, SLEN, 0, enc_emb,
        enc_Wih, enc_b, xp_e);
  k_chain3<<<NWG, 1024, 0, stream>>>(xp_e, SLEN,
        enc_Whh, enc_Wih + (size_t)G4*EMBD, enc_Whh + (size_t)G4*HID,
        enc_b + G4, h0P, h1P, c0P, c1P, h0T, h1T, ctr, 1);

  // decoder greedy loop (outer step t replays positions 0..t)
  int coff = SLEN;
  for (int t = 0; t < NPRED; t++){
    k_xproj<<<dim3(32, 1), 256, 0, stream>>>(buf, TLEN, t, dec_emb,
        dec_Wih, dec_b, xp_d);
    k_chain3<<<NWG, 1024, 0, stream>>>(xp_d, t+1,
        dec_Whh, dec_Wih + (size_t)G4*EMBD, dec_Whh + (size_t)G4*HID,
        dec_b + G4, h0P, h1P, c0P, c1P, h0T, h1T, ctr + coff, 0);
    coff += t + 1;
    k_pred<<<1000, 256, 0, stream>>>(h1P, W_out, b_out, out, t, pval, pidx);
    k_amax<<<B, 256, 0, stream>>>(pval, pidx, buf, t);
  }
}